// Round 3
// baseline (648.247 us; speedup 1.0000x reference)
//
#include <hip/hip_runtime.h>

#define VOCAB 50000
#define EMBED 256
#define HIDDEN 512
#define BATCH 128
#define SEQ 400
#define XDIM 768
#define NSC (VOCAB + SEQ)   // 50400

typedef __attribute__((ext_vector_type(8))) short bf16x8;
typedef __attribute__((ext_vector_type(4))) float f32x4;

__device__ __forceinline__ float fsig(float x){ return 1.0f/(1.0f+__expf(-x)); }
__device__ __forceinline__ float ftanh(float x){ return 1.0f - 2.0f/(__expf(2.0f*x)+1.0f); }

__device__ __forceinline__ unsigned short f2bf(float f){
  union { float f; unsigned u; } v; v.f = f;
  unsigned r = v.u + 0x7fffu + ((v.u >> 16) & 1u);   // RNE
  return (unsigned short)(r >> 16);
}

__device__ __forceinline__ bf16x8 load_frag_f32(const float* p){
  const f32x4 a = *(const f32x4*)(p);
  const f32x4 b = *(const f32x4*)(p + 4);
  bf16x8 r;
  r[0]=(short)f2bf(a[0]); r[1]=(short)f2bf(a[1]); r[2]=(short)f2bf(a[2]); r[3]=(short)f2bf(a[3]);
  r[4]=(short)f2bf(b[0]); r[5]=(short)f2bf(b[1]); r[6]=(short)f2bf(b[2]); r[7]=(short)f2bf(b[3]);
  return r;
}

// ---------------- K1: build xT[768][128], hT[512][128] (transposed, b fast) ---
__global__ __launch_bounds__(256) void k_buildT(
    const int* __restrict__ idx, const float* __restrict__ weighted,
    const int* __restrict__ order, const float* __restrict__ embW,
    const float* __restrict__ prev,
    float* __restrict__ xT, float* __restrict__ hT)
{
  int i = blockIdx.x*256 + threadIdx.x;            // < 163840
  int c = i >> 7, b = i & 127;
  if (c < XDIM) {
    float v;
    if (c < EMBED) v = embW[(size_t)idx[b]*EMBED + c];
    else           v = (order[0] != 0) ? weighted[b*HIDDEN + (c-EMBED)] : 0.0f;
    xT[(size_t)c*128 + b] = v;
  } else {
    int cc = c - XDIM;
    hT[(size_t)cc*128 + b] = prev[(size_t)b*HIDDEN + cc];
  }
}

// ---------------- K1b: zero gi/gh/spart accumulators (ws is poisoned) ---------
__global__ __launch_bounds__(256) void k_zero(float* __restrict__ p)
{
  int i = blockIdx.x*256 + threadIdx.x;            // 111104 threads x4 = 444416
  *(f32x4*)(p + (size_t)i*4) = f32x4{0,0,0,0};
}

// ---------------- K2: Wc -> bf16 ----------------
__global__ __launch_bounds__(256) void k_cvt_wc(const float* __restrict__ w,
                                                unsigned short* __restrict__ w16)
{
  int i = blockIdx.x*256 + threadIdx.x;            // < 262144
  w16[i] = f2bf(w[i]);
}

// ---------------- K3a: GRU gate GEMV, K-split + atomic reduce ----------------
__global__ __launch_bounds__(256) void k_gemv(
    const float* __restrict__ Wih, const float* __restrict__ Whh,
    const float* __restrict__ xT, const float* __restrict__ hT,
    float* __restrict__ gi, float* __restrict__ gh)
{
  int t = threadIdx.x;
  int b = t & 127, jh = t >> 7;
  int y = blockIdx.y;
  const float* W; const float* xp; float* outp; int K, KC, k0;
  if (y < 4) { W = Wih; xp = xT; outp = gi; K = XDIM;   KC = 192; k0 = y*192; }
  else       { W = Whh; xp = hT; outp = gh; K = HIDDEN; KC = 128; k0 = (y-4)*128; }
  int j0 = __builtin_amdgcn_readfirstlane((int)(blockIdx.x*8 + jh*4));
  const float* w0 = W + (size_t)(j0+0)*K;
  const float* w1 = W + (size_t)(j0+1)*K;
  const float* w2 = W + (size_t)(j0+2)*K;
  const float* w3 = W + (size_t)(j0+3)*K;
  float a0=0,a1=0,a2=0,a3=0;
  for (int k = k0; k < k0+KC; k += 4) {
    #pragma unroll
    for (int u = 0; u < 4; ++u) {
      float xv = xp[(size_t)(k+u)*128 + b];
      a0 += w0[k+u]*xv; a1 += w1[k+u]*xv; a2 += w2[k+u]*xv; a3 += w3[k+u]*xv;
    }
  }
  atomicAdd(&outp[(size_t)(j0+0)*128 + b], a0);
  atomicAdd(&outp[(size_t)(j0+1)*128 + b], a1);
  atomicAdd(&outp[(size_t)(j0+2)*128 + b], a2);
  atomicAdd(&outp[(size_t)(j0+3)*128 + b], a3);
}

// ---------------- K3b: GRU elementwise -> state ----------------
__global__ __launch_bounds__(256) void k_state(
    const float* __restrict__ gi, const float* __restrict__ gh,
    const float* __restrict__ bih, const float* __restrict__ bhh,
    const float* __restrict__ prev,
    float* __restrict__ state_f, unsigned short* __restrict__ st16,
    float* __restrict__ out_state)
{
  int i = blockIdx.x*256 + threadIdx.x;            // < 65536
  int b = i & 127, hh = i >> 7;
  float ir = gi[(size_t)hh*128 + b]          + bih[hh];
  float hr = gh[(size_t)hh*128 + b]          + bhh[hh];
  float iz = gi[(size_t)(512+hh)*128 + b]    + bih[512+hh];
  float hz = gh[(size_t)(512+hh)*128 + b]    + bhh[512+hh];
  float in_= gi[(size_t)(1024+hh)*128 + b]   + bih[1024+hh];
  float hn = gh[(size_t)(1024+hh)*128 + b]   + bhh[1024+hh];
  float r = fsig(ir + hr);
  float z = fsig(iz + hz);
  float n = ftanh(in_ + r*hn);
  float st = (1.0f - z)*n + z*prev[(size_t)b*HIDDEN + hh];
  state_f[(size_t)b*HIDDEN + hh] = st;
  st16[(size_t)b*HIDDEN + hh]    = f2bf(st);
  out_state[(size_t)b*HIDDEN + hh] = st;
}

// ---------------- K4: score_c MFMA, split-N (2 h-chunks), atomic partial ------
// grid (400 m-tiles of 128 rows, 2 n-chunks of 256 h). wave = 32 rows.
__global__ __launch_bounds__(256, 3) void k_score_c(
    const float* __restrict__ enc, const unsigned short* __restrict__ wc16,
    const float* __restrict__ wcb, const float* __restrict__ state,
    float* __restrict__ spart)
{
  int tid = threadIdx.x, wave = tid >> 6, lane = tid & 63;
  int lo = lane & 15, q = lane >> 4;
  int m_base = blockIdx.x*128 + wave*32;
  int h_base = blockIdx.y*256;

  bf16x8 A[2][16];
  #pragma unroll
  for (int mf = 0; mf < 2; ++mf) {
    const float* rowp = enc + (size_t)(m_base + mf*16 + lo)*HIDDEN + q*8;
    #pragma unroll
    for (int kc = 0; kc < 16; ++kc) A[mf][kc] = load_frag_f32(rowp + kc*32);
  }

  float sp[8] = {0,0,0,0,0,0,0,0};
  for (int nt = 0; nt < 16; ++nt) {
    int h0 = h_base + nt*16;
    f32x4 acc[2] = {{0,0,0,0},{0,0,0,0}};
    const unsigned short* bp = wc16 + (size_t)(h0 + lo)*HIDDEN + q*8;
    #pragma unroll
    for (int kc = 0; kc < 16; ++kc) {
      bf16x8 bf = *(const bf16x8*)(bp + kc*32);
      acc[0] = __builtin_amdgcn_mfma_f32_16x16x32_bf16(A[0][kc], bf, acc[0], 0, 0, 0);
      acc[1] = __builtin_amdgcn_mfma_f32_16x16x32_bf16(A[1][kc], bf, acc[1], 0, 0, 0);
    }
    int hcol = h0 + lo;
    float bias = wcb[hcol];
    #pragma unroll
    for (int mf = 0; mf < 2; ++mf) {
      #pragma unroll
      for (int r = 0; r < 4; ++r) {
        int sg = m_base + mf*16 + q*4 + r;
        int b = sg / SEQ;
        float y = ftanh(acc[mf][r] + bias) * state[(size_t)b*HIDDEN + hcol];
        sp[mf*4 + r] += y;
      }
    }
  }
  #pragma unroll
  for (int i = 0; i < 8; ++i) {
    float v = sp[i];
    v += __shfl_xor(v, 1, 16); v += __shfl_xor(v, 2, 16);
    v += __shfl_xor(v, 4, 16); v += __shfl_xor(v, 8, 16);
    sp[i] = v;
  }
  if (lo == 0) {
    #pragma unroll
    for (int mf = 0; mf < 2; ++mf) {
      #pragma unroll
      for (int r = 0; r < 4; ++r) {
        int sg = m_base + mf*16 + q*4 + r;
        atomicAdd(&spart[sg], sp[mf*4 + r]);
      }
    }
  }
}

// ---------------- K4b: finalize score_c: tanh + mask -> scoresT --------------
__global__ __launch_bounds__(256) void k_finish(
    const float* __restrict__ spart, const int* __restrict__ enc_idx,
    float* __restrict__ scoresT)
{
  int sg = blockIdx.x*256 + threadIdx.x;           // < 51200
  int b = sg / SEQ, s = sg - b*SEQ;
  float val = ftanh(spart[sg]);
  if (enc_idx[sg] == 0) val -= 1000.0f;
  scoresT[(size_t)(VOCAB + s)*BATCH + b] = val;
}

// ---------------- K5: score_g MFMA, 16 v-rows per wave ----------------
// grid 782 blocks x 64 v-rows (4 waves x 16).
__global__ __launch_bounds__(256) void k_score_g(
    const float* __restrict__ Wo, const float* __restrict__ Wob,
    const unsigned short* __restrict__ st16, float* __restrict__ scoresT)
{
  int tid = threadIdx.x, wave = tid >> 6, lane = tid & 63;
  int lo = lane & 15, q = lane >> 4;
  int v_base = blockIdx.x*64 + wave*16;

  bf16x8 A[16];
  {
    int v = v_base + lo;
    if (v >= VOCAB) v = VOCAB - 1;          // clamp pad rows (stores guarded)
    const float* rowp = Wo + (size_t)v*HIDDEN + q*8;
    #pragma unroll
    for (int kc = 0; kc < 16; ++kc) A[kc] = load_frag_f32(rowp + kc*32);
  }
  #pragma unroll
  for (int nt = 0; nt < 8; nt += 2) {
    f32x4 acc[2] = {{0,0,0,0},{0,0,0,0}};
    const unsigned short* bp0 = st16 + (size_t)((nt  )*16 + lo)*HIDDEN + q*8;
    const unsigned short* bp1 = st16 + (size_t)((nt+1)*16 + lo)*HIDDEN + q*8;
    #pragma unroll
    for (int kc = 0; kc < 16; ++kc) {
      bf16x8 b0 = *(const bf16x8*)(bp0 + kc*32);
      bf16x8 b1 = *(const bf16x8*)(bp1 + kc*32);
      acc[0] = __builtin_amdgcn_mfma_f32_16x16x32_bf16(A[kc], b0, acc[0], 0, 0, 0);
      acc[1] = __builtin_amdgcn_mfma_f32_16x16x32_bf16(A[kc], b1, acc[1], 0, 0, 0);
    }
    #pragma unroll
    for (int t = 0; t < 2; ++t) {
      int b = (nt + t)*16 + lo;
      #pragma unroll
      for (int r = 0; r < 4; ++r) {
        int v = v_base + q*4 + r;
        if (v < VOCAB) scoresT[(size_t)v*BATCH + b] = acc[t][r] + Wob[v];
      }
    }
  }
}

// ---------------- K6: sum of exp (no max pass; scores bounded) ----------------
__global__ __launch_bounds__(256) void k_sumexp(const float* __restrict__ scoresT,
                                                float* __restrict__ pl)
{
  __shared__ float red[256];
  int t = threadIdx.x, b = t & 127, half = t >> 7;
  int base = blockIdx.x*128;                       // 394 blocks
  int lim = base + 128; if (lim > NSC) lim = NSC;
  float s = 0.0f;
  for (int r = base + half; r < lim; r += 2)
    s += __expf(scoresT[(size_t)r*BATCH + b]);
  red[t] = s; __syncthreads();
  if (t < 128) pl[blockIdx.x*128 + t] = red[t] + red[t + 128];
}

__global__ __launch_bounds__(1024) void k_merge(const float* __restrict__ pl,
                                                float* __restrict__ linv)
{
  __shared__ float red[1024];
  int t = threadIdx.x, b = t & 127, g = t >> 7;    // 8 groups
  float s = 0.0f;
  for (int i = g; i < 394; i += 8) s += pl[(size_t)i*128 + b];
  red[t] = s; __syncthreads();
  if (t < 512) red[t] += red[t + 512];
  __syncthreads();
  if (t < 256) red[t] += red[t + 256];
  __syncthreads();
  if (t < 128) linv[b] = 1.0f / (red[t] + red[t + 128]);
}

// ---------------- K8: prob_g -> out (LDS transpose for coalesced stores) ------
__global__ __launch_bounds__(256) void k_probg(const float* __restrict__ scoresT,
                                               const float* __restrict__ linv,
                                               float* __restrict__ out)
{
  __shared__ float tile[128*65];
  int t = threadIdx.x, v0 = blockIdx.x*64;
  int b = t & 127, half = t >> 7;
  float li = linv[b];
  for (int i = half; i < 64; i += 2) {
    int v = v0 + i;
    tile[b*65 + i] = (v < VOCAB) ? __expf(scoresT[(size_t)v*BATCH + b]) * li : 0.0f;
  }
  __syncthreads();
  int vq = t & 15, bq = t >> 4;
  #pragma unroll
  for (int p = 0; p < 8; ++p) {
    int b2 = bq + p*16;
    int v = v0 + vq*4;
    if (v < VOCAB) {
      f32x4 o = { tile[b2*65 + vq*4], tile[b2*65 + vq*4 + 1],
                  tile[b2*65 + vq*4 + 2], tile[b2*65 + vq*4 + 3] };
      *(f32x4*)(out + (size_t)b2*VOCAB + v) = o;
    }
  }
}

// ---------------- K9: scatter prob_c into out + weighted_out (compacted) ------
__global__ __launch_bounds__(256) void k_scatter(
    const float* __restrict__ scoresT, const float* __restrict__ linv,
    const int* __restrict__ enc_idx, const int* __restrict__ inp_idx,
    const float* __restrict__ enc, float* __restrict__ out,
    float* __restrict__ wout)
{
  __shared__ float am[SEQ];
  __shared__ int   sm[SEQ];
  __shared__ int   redc[256];
  __shared__ int   ns;
  int b = blockIdx.x, t = threadIdx.x;
  int target = inp_idx[b];
  if (t == 0) ns = 0;
  int cnt = 0;
  for (int s = t; s < SEQ; s += 256) cnt += (enc_idx[b*SEQ + s] == target);
  redc[t] = cnt; __syncthreads();
  for (int o = 128; o > 0; o >>= 1) { if (t < o) redc[t] += redc[t + o]; __syncthreads(); }
  int count = redc[0];
  float rnorm = (count > 1) ? 1.0f/(float)count : 1.0f;
  float li = linv[b];
  for (int s = t; s < SEQ; s += 256) {
    float p = __expf(scoresT[(size_t)(VOCAB + s)*BATCH + b]) * li;
    int ix = enc_idx[b*SEQ + s];
    atomicAdd(&out[(size_t)b*VOCAB + ix], p);
    if (ix == target) { int slot = atomicAdd(&ns, 1); sm[slot] = s; am[slot] = p*rnorm; }
  }
  __syncthreads();
  int n = ns;
  for (int hh = t; hh < HIDDEN; hh += 256) {
    float acc = 0.0f;
    for (int m = 0; m < n; ++m)
      acc += am[m] * enc[((size_t)b*SEQ + sm[m])*HIDDEN + hh];
    wout[(size_t)b*HIDDEN + hh] = acc;
  }
}

extern "C" void kernel_launch(void* const* d_in, const int* in_sizes, int n_in,
                              void* d_out, int out_size, void* d_ws, size_t ws_size,
                              hipStream_t stream) {
  const int*   input_idx = (const int*)  d_in[0];
  const float* enc       = (const float*)d_in[1];
  const int*   enc_idx   = (const int*)  d_in[2];
  const float* prev      = (const float*)d_in[3];
  const float* weighted  = (const float*)d_in[4];
  const int*   order     = (const int*)  d_in[5];
  const float* embW      = (const float*)d_in[6];
  const float* Wih       = (const float*)d_in[7];
  const float* Whh       = (const float*)d_in[8];
  const float* bih       = (const float*)d_in[9];
  const float* bhh       = (const float*)d_in[10];
  const float* WoW       = (const float*)d_in[11];
  const float* Wob       = (const float*)d_in[12];
  const float* WcW       = (const float*)d_in[13];
  const float* Wcb       = (const float*)d_in[14];

  float* out       = (float*)d_out;
  float* out_state = out + (size_t)BATCH*VOCAB;            // 6,400,000
  float* out_w     = out_state + (size_t)BATCH*HIDDEN;     // 6,465,536

  float* ws       = (float*)d_ws;
  float* xT       = ws;                    // 98304
  float* hT       = ws + 98304;            // 65536
  float* gi       = ws + 163840;           // 196608  (1536 x 128)
  float* gh       = ws + 360448;           // 196608
  float* spart    = ws + 557056;           // 51200   (contiguous w/ gi,gh for k_zero)
  float* state_f  = ws + 608256;           // 65536
  float* scoresT  = ws + 673792;           // 6451200 (50400 x 128)
  float* pl       = ws + 7124992;          // 50432   (394 x 128)
  float* linv     = ws + 7175424;          // 128
  unsigned short* wc16 = (unsigned short*)(ws + 7175552); // 262144 u16
  unsigned short* st16 = (unsigned short*)(ws + 7306624); // 65536 u16
  // total ws use: ~7,339,392 floats = 29.4 MB

  k_buildT <<<640, 256, 0, stream>>>(input_idx, weighted, order, embW, prev, xT, hT);
  k_zero   <<<434, 256, 0, stream>>>(gi);           // zeros gi, gh, spart (contiguous)
  k_cvt_wc <<<1024, 256, 0, stream>>>(WcW, wc16);
  k_gemv   <<<dim3(192, 8), 256, 0, stream>>>(Wih, Whh, xT, hT, gi, gh);
  k_state  <<<256, 256, 0, stream>>>(gi, gh, bih, bhh, prev, state_f, st16, out_state);
  k_score_g<<<782, 256, 0, stream>>>(WoW, Wob, st16, scoresT);
  k_score_c<<<dim3(400, 2), 256, 0, stream>>>(enc, wc16, Wcb, state_f, spart);
  k_finish <<<200, 256, 0, stream>>>(spart, enc_idx, scoresT);
  k_sumexp <<<394, 256, 0, stream>>>(scoresT, pl);
  k_merge  <<<1, 1024, 0, stream>>>(pl, linv);
  k_probg  <<<782, 256, 0, stream>>>(scoresT, linv, out);
  k_scatter<<<128, 256, 0, stream>>>(scoresT, linv, enc_idx, input_idx, enc, out, out_w);
}

// Round 4
// 487.340 us; speedup vs baseline: 1.3302x; 1.3302x over previous
//
#include <hip/hip_runtime.h>

#define VOCAB 50000
#define EMBED 256
#define HIDDEN 512
#define BATCH 128
#define SEQ 400
#define XDIM 768
#define NSC (VOCAB + SEQ)   // 50400

typedef __attribute__((ext_vector_type(8))) short bf16x8;
typedef __attribute__((ext_vector_type(4))) float f32x4;

__device__ __forceinline__ float fsig(float x){ return 1.0f/(1.0f+__expf(-x)); }
__device__ __forceinline__ float ftanh(float x){ return 1.0f - 2.0f/(__expf(2.0f*x)+1.0f); }

__device__ __forceinline__ unsigned short f2bf(float f){
  union { float f; unsigned u; } v; v.f = f;
  unsigned r = v.u + 0x7fffu + ((v.u >> 16) & 1u);   // RNE
  return (unsigned short)(r >> 16);
}

__device__ __forceinline__ bf16x8 load_frag_f32(const float* p){
  const f32x4 a = *(const f32x4*)(p);
  const f32x4 b = *(const f32x4*)(p + 4);
  bf16x8 r;
  r[0]=(short)f2bf(a[0]); r[1]=(short)f2bf(a[1]); r[2]=(short)f2bf(a[2]); r[3]=(short)f2bf(a[3]);
  r[4]=(short)f2bf(b[0]); r[5]=(short)f2bf(b[1]); r[6]=(short)f2bf(b[2]); r[7]=(short)f2bf(b[3]);
  return r;
}

// ---------------- K1: build xT[768][128], hT[512][128] (transposed, b fast) ---
__global__ __launch_bounds__(256) void k_buildT(
    const int* __restrict__ idx, const float* __restrict__ weighted,
    const int* __restrict__ order, const float* __restrict__ embW,
    const float* __restrict__ prev,
    float* __restrict__ xT, float* __restrict__ hT)
{
  int i = blockIdx.x*256 + threadIdx.x;            // < 163840
  int c = i >> 7, b = i & 127;
  if (c < XDIM) {
    float v;
    if (c < EMBED) v = embW[(size_t)idx[b]*EMBED + c];
    else           v = (order[0] != 0) ? weighted[b*HIDDEN + (c-EMBED)] : 0.0f;
    xT[(size_t)c*128 + b] = v;
  } else {
    int cc = c - XDIM;
    hT[(size_t)cc*128 + b] = prev[(size_t)b*HIDDEN + cc];
  }
}

// ---------------- K1b: zero gi/gh accumulators (ws is poisoned) ----------------
__global__ __launch_bounds__(256) void k_zero(float* __restrict__ p)
{
  int i = blockIdx.x*256 + threadIdx.x;            // 98304 threads x4 = 393216
  *(f32x4*)(p + (size_t)i*4) = f32x4{0,0,0,0};
}

// ---------------- K2: Wc -> bf16 ----------------
__global__ __launch_bounds__(256) void k_cvt_wc(const float* __restrict__ w,
                                                unsigned short* __restrict__ w16)
{
  int i = blockIdx.x*256 + threadIdx.x;            // < 262144
  w16[i] = f2bf(w[i]);
}

// ---------------- K3a: GRU gate GEMV, K-split + atomic reduce ----------------
__global__ __launch_bounds__(256) void k_gemv(
    const float* __restrict__ Wih, const float* __restrict__ Whh,
    const float* __restrict__ xT, const float* __restrict__ hT,
    float* __restrict__ gi, float* __restrict__ gh)
{
  int t = threadIdx.x;
  int b = t & 127, jh = t >> 7;
  int y = blockIdx.y;
  const float* W; const float* xp; float* outp; int K, KC, k0;
  if (y < 4) { W = Wih; xp = xT; outp = gi; K = XDIM;   KC = 192; k0 = y*192; }
  else       { W = Whh; xp = hT; outp = gh; K = HIDDEN; KC = 128; k0 = (y-4)*128; }
  int j0 = __builtin_amdgcn_readfirstlane((int)(blockIdx.x*8 + jh*4));
  const float* w0 = W + (size_t)(j0+0)*K;
  const float* w1 = W + (size_t)(j0+1)*K;
  const float* w2 = W + (size_t)(j0+2)*K;
  const float* w3 = W + (size_t)(j0+3)*K;
  float a0=0,a1=0,a2=0,a3=0;
  for (int k = k0; k < k0+KC; k += 4) {
    #pragma unroll
    for (int u = 0; u < 4; ++u) {
      float xv = xp[(size_t)(k+u)*128 + b];
      a0 += w0[k+u]*xv; a1 += w1[k+u]*xv; a2 += w2[k+u]*xv; a3 += w3[k+u]*xv;
    }
  }
  atomicAdd(&outp[(size_t)(j0+0)*128 + b], a0);
  atomicAdd(&outp[(size_t)(j0+1)*128 + b], a1);
  atomicAdd(&outp[(size_t)(j0+2)*128 + b], a2);
  atomicAdd(&outp[(size_t)(j0+3)*128 + b], a3);
}

// ---------------- K3b: GRU elementwise -> state ----------------
__global__ __launch_bounds__(256) void k_state(
    const float* __restrict__ gi, const float* __restrict__ gh,
    const float* __restrict__ bih, const float* __restrict__ bhh,
    const float* __restrict__ prev,
    float* __restrict__ state_f, unsigned short* __restrict__ st16,
    float* __restrict__ out_state)
{
  int i = blockIdx.x*256 + threadIdx.x;            // < 65536
  int b = i & 127, hh = i >> 7;
  float ir = gi[(size_t)hh*128 + b]          + bih[hh];
  float hr = gh[(size_t)hh*128 + b]          + bhh[hh];
  float iz = gi[(size_t)(512+hh)*128 + b]    + bih[512+hh];
  float hz = gh[(size_t)(512+hh)*128 + b]    + bhh[512+hh];
  float in_= gi[(size_t)(1024+hh)*128 + b]   + bih[1024+hh];
  float hn = gh[(size_t)(1024+hh)*128 + b]   + bhh[1024+hh];
  float r = fsig(ir + hr);
  float z = fsig(iz + hz);
  float n = ftanh(in_ + r*hn);
  float st = (1.0f - z)*n + z*prev[(size_t)b*HIDDEN + hh];
  state_f[(size_t)b*HIDDEN + hh] = st;
  st16[(size_t)b*HIDDEN + hh]    = f2bf(st);
  out_state[(size_t)b*HIDDEN + hh] = st;
}

// ---------------- K4: score_c MFMA, A<=64 VGPR, B double-buffered in LDS ------
// block = 4 waves x 16 s-rows = 64 rows; nt-loop over 32 h-tiles of 16.
#define BPAD 520   // padded LDS row stride (halves): 1040 B == 4 mod 32 banks
__global__ __launch_bounds__(256) void k_score_c(
    const float* __restrict__ enc, const unsigned short* __restrict__ wc16,
    const float* __restrict__ wcb, const float* __restrict__ state,
    const int* __restrict__ enc_idx, float* __restrict__ scoresT)
{
  __shared__ unsigned short Bs[2][16*BPAD];
  __shared__ float st_s[2*HIDDEN];
  __shared__ float bias_s[HIDDEN];

  int tid = threadIdx.x, wave = tid >> 6, lane = tid & 63;
  int lo = lane & 15, q = lane >> 4;
  int m_blk = blockIdx.x*64;
  int my_row = m_blk + wave*16 + lo;

  // A fragments: 16 rows x K=512 -> exactly 64 VGPRs, loaded once.
  bf16x8 A[16];
  {
    const float* rowp = enc + (size_t)my_row*HIDDEN + q*8;
    #pragma unroll
    for (int kc = 0; kc < 16; ++kc) A[kc] = load_frag_f32(rowp + kc*32);
  }

  int b0 = m_blk / SEQ;                            // block spans b0 (and maybe b0+1)
  {
    int b1 = (m_blk + 63) / SEQ; if (b1 > BATCH-1) b1 = BATCH-1;
    for (int i = tid; i < HIDDEN; i += 256) {
      bias_s[i]        = wcb[i];
      st_s[i]          = state[(size_t)b0*HIDDEN + i];
      st_s[HIDDEN + i] = state[(size_t)b1*HIDDEN + i];
    }
  }
  int srow = tid >> 4, sc = tid & 15;              // staging coords
  {
    const f32x4* src = (const f32x4*)(wc16 + (size_t)srow*HIDDEN + sc*32);
    f32x4* dst = (f32x4*)(Bs[0] + srow*BPAD + sc*32);
    dst[0] = src[0]; dst[1] = src[1]; dst[2] = src[2]; dst[3] = src[3];
  }
  __syncthreads();

  float sp[4] = {0,0,0,0};
  int pb = 0;
  for (int nt = 0; nt < 32; ++nt) {
    f32x4 pf0, pf1, pf2, pf3;
    if (nt < 31) {
      const f32x4* src = (const f32x4*)(wc16 + (size_t)((nt+1)*16 + srow)*HIDDEN + sc*32);
      pf0 = src[0]; pf1 = src[1]; pf2 = src[2]; pf3 = src[3];
    }
    // two independent MFMA chains over K
    f32x4 acc0 = {0,0,0,0}, acc1 = {0,0,0,0};
    const unsigned short* bp = Bs[pb] + lo*BPAD + q*8;
    #pragma unroll
    for (int kc = 0; kc < 16; kc += 2) {
      bf16x8 bf0 = *(const bf16x8*)(bp + (kc  )*32);
      bf16x8 bf1 = *(const bf16x8*)(bp + (kc+1)*32);
      acc0 = __builtin_amdgcn_mfma_f32_16x16x32_bf16(A[kc  ], bf0, acc0, 0, 0, 0);
      acc1 = __builtin_amdgcn_mfma_f32_16x16x32_bf16(A[kc+1], bf1, acc1, 0, 0, 0);
    }
    int hcol = nt*16 + lo;
    float bias = bias_s[hcol];
    #pragma unroll
    for (int r = 0; r < 4; ++r) {
      int sg = m_blk + wave*16 + q*4 + r;
      int bsel = (sg >= (b0+1)*SEQ) ? 1 : 0;
      sp[r] += ftanh(acc0[r] + acc1[r] + bias) * st_s[bsel*HIDDEN + hcol];
    }
    if (nt < 31) {
      f32x4* dst = (f32x4*)(Bs[pb^1] + srow*BPAD + sc*32);
      dst[0] = pf0; dst[1] = pf1; dst[2] = pf2; dst[3] = pf3;
    }
    pb ^= 1;
    __syncthreads();
  }

  #pragma unroll
  for (int r = 0; r < 4; ++r) {
    float v = sp[r];
    v += __shfl_xor(v, 1, 16); v += __shfl_xor(v, 2, 16);
    v += __shfl_xor(v, 4, 16); v += __shfl_xor(v, 8, 16);
    sp[r] = v;
  }
  if (lo == 0) {
    #pragma unroll
    for (int r = 0; r < 4; ++r) {
      int sg = m_blk + wave*16 + q*4 + r;
      int b = sg / SEQ, s = sg - b*SEQ;
      float val = ftanh(sp[r]);
      if (enc_idx[sg] == 0) val -= 1000.0f;
      scoresT[(size_t)(VOCAB + s)*BATCH + b] = val;
    }
  }
}

// ---------------- K5: score_g MFMA, streamed A (never held), B from L2 --------
// wave = 16 v-rows; acc[8] covers all 128 batch cols; HBM-bound on Wo.
__global__ __launch_bounds__(256) void k_score_g(
    const float* __restrict__ Wo, const float* __restrict__ Wob,
    const unsigned short* __restrict__ st16, float* __restrict__ scoresT)
{
  int tid = threadIdx.x, wave = tid >> 6, lane = tid & 63;
  int lo = lane & 15, q = lane >> 4;
  int v_base = (blockIdx.x*4 + wave)*16;
  int vrow = v_base + lo; if (vrow > VOCAB-1) vrow = VOCAB-1;
  const float* ap = Wo + (size_t)vrow*HIDDEN + q*8;

  f32x4 acc[8] = {{0,0,0,0},{0,0,0,0},{0,0,0,0},{0,0,0,0},
                  {0,0,0,0},{0,0,0,0},{0,0,0,0},{0,0,0,0}};
  #pragma unroll 2
  for (int kc = 0; kc < 16; ++kc) {
    bf16x8 af = load_frag_f32(ap + kc*32);
    #pragma unroll
    for (int t = 0; t < 8; ++t) {
      bf16x8 bf = *(const bf16x8*)(st16 + (size_t)(t*16 + lo)*HIDDEN + kc*32 + q*8);
      acc[t] = __builtin_amdgcn_mfma_f32_16x16x32_bf16(af, bf, acc[t], 0, 0, 0);
    }
  }
  #pragma unroll
  for (int r = 0; r < 4; ++r) {
    int v = v_base + q*4 + r;
    if (v < VOCAB) {
      float bias = Wob[v];
      #pragma unroll
      for (int t = 0; t < 8; ++t)
        scoresT[(size_t)v*BATCH + t*16 + lo] = acc[t][r] + bias;
    }
  }
}

// ---------------- K6: sum of exp (no max pass; scores bounded) ----------------
__global__ __launch_bounds__(256) void k_sumexp(const float* __restrict__ scoresT,
                                                float* __restrict__ pl)
{
  __shared__ float red[256];
  int t = threadIdx.x, b = t & 127, half = t >> 7;
  int base = blockIdx.x*128;                       // 394 blocks
  int lim = base + 128; if (lim > NSC) lim = NSC;
  float s = 0.0f;
  for (int r = base + half; r < lim; r += 2)
    s += __expf(scoresT[(size_t)r*BATCH + b]);
  red[t] = s; __syncthreads();
  if (t < 128) pl[blockIdx.x*128 + t] = red[t] + red[t + 128];
}

__global__ __launch_bounds__(1024) void k_merge(const float* __restrict__ pl,
                                                float* __restrict__ linv)
{
  __shared__ float red[1024];
  int t = threadIdx.x, b = t & 127, g = t >> 7;    // 8 groups
  float s = 0.0f;
  for (int i = g; i < 394; i += 8) s += pl[(size_t)i*128 + b];
  red[t] = s; __syncthreads();
  if (t < 512) red[t] += red[t + 512];
  __syncthreads();
  if (t < 256) red[t] += red[t + 256];
  __syncthreads();
  if (t < 128) linv[b] = 1.0f / (red[t] + red[t + 128]);
}

// ---------------- K8: prob_g -> out (LDS transpose for coalesced stores) ------
__global__ __launch_bounds__(256) void k_probg(const float* __restrict__ scoresT,
                                               const float* __restrict__ linv,
                                               float* __restrict__ out)
{
  __shared__ float tile[128*65];
  int t = threadIdx.x, v0 = blockIdx.x*64;
  int b = t & 127, half = t >> 7;
  float li = linv[b];
  for (int i = half; i < 64; i += 2) {
    int v = v0 + i;
    tile[b*65 + i] = (v < VOCAB) ? __expf(scoresT[(size_t)v*BATCH + b]) * li : 0.0f;
  }
  __syncthreads();
  int vq = t & 15, bq = t >> 4;
  #pragma unroll
  for (int p = 0; p < 8; ++p) {
    int b2 = bq + p*16;
    int v = v0 + vq*4;
    if (v < VOCAB) {
      f32x4 o = { tile[b2*65 + vq*4], tile[b2*65 + vq*4 + 1],
                  tile[b2*65 + vq*4 + 2], tile[b2*65 + vq*4 + 3] };
      *(f32x4*)(out + (size_t)b2*VOCAB + v) = o;
    }
  }
}

// ---------------- K9: scatter prob_c into out + weighted_out (compacted) ------
__global__ __launch_bounds__(256) void k_scatter(
    const float* __restrict__ scoresT, const float* __restrict__ linv,
    const int* __restrict__ enc_idx, const int* __restrict__ inp_idx,
    const float* __restrict__ enc, float* __restrict__ out,
    float* __restrict__ wout)
{
  __shared__ float am[SEQ];
  __shared__ int   sm[SEQ];
  __shared__ int   redc[256];
  __shared__ int   ns;
  int b = blockIdx.x, t = threadIdx.x;
  int target = inp_idx[b];
  if (t == 0) ns = 0;
  int cnt = 0;
  for (int s = t; s < SEQ; s += 256) cnt += (enc_idx[b*SEQ + s] == target);
  redc[t] = cnt; __syncthreads();
  for (int o = 128; o > 0; o >>= 1) { if (t < o) redc[t] += redc[t + o]; __syncthreads(); }
  int count = redc[0];
  float rnorm = (count > 1) ? 1.0f/(float)count : 1.0f;
  float li = linv[b];
  for (int s = t; s < SEQ; s += 256) {
    float p = __expf(scoresT[(size_t)(VOCAB + s)*BATCH + b]) * li;
    int ix = enc_idx[b*SEQ + s];
    atomicAdd(&out[(size_t)b*VOCAB + ix], p);
    if (ix == target) { int slot = atomicAdd(&ns, 1); sm[slot] = s; am[slot] = p*rnorm; }
  }
  __syncthreads();
  int n = ns;
  for (int hh = t; hh < HIDDEN; hh += 256) {
    float acc = 0.0f;
    for (int m = 0; m < n; ++m)
      acc += am[m] * enc[((size_t)b*SEQ + sm[m])*HIDDEN + hh];
    wout[(size_t)b*HIDDEN + hh] = acc;
  }
}

extern "C" void kernel_launch(void* const* d_in, const int* in_sizes, int n_in,
                              void* d_out, int out_size, void* d_ws, size_t ws_size,
                              hipStream_t stream) {
  const int*   input_idx = (const int*)  d_in[0];
  const float* enc       = (const float*)d_in[1];
  const int*   enc_idx   = (const int*)  d_in[2];
  const float* prev      = (const float*)d_in[3];
  const float* weighted  = (const float*)d_in[4];
  const int*   order     = (const int*)  d_in[5];
  const float* embW      = (const float*)d_in[6];
  const float* Wih       = (const float*)d_in[7];
  const float* Whh       = (const float*)d_in[8];
  const float* bih       = (const float*)d_in[9];
  const float* bhh       = (const float*)d_in[10];
  const float* WoW       = (const float*)d_in[11];
  const float* Wob       = (const float*)d_in[12];
  const float* WcW       = (const float*)d_in[13];
  const float* Wcb       = (const float*)d_in[14];

  float* out       = (float*)d_out;
  float* out_state = out + (size_t)BATCH*VOCAB;            // 6,400,000
  float* out_w     = out_state + (size_t)BATCH*HIDDEN;     // 6,465,536

  float* ws       = (float*)d_ws;
  float* xT       = ws;                    // 98304
  float* hT       = ws + 98304;            // 65536
  float* gi       = ws + 163840;           // 196608  (1536 x 128)
  float* gh       = ws + 360448;           // 196608
  float* state_f  = ws + 557056;           // 65536
  float* scoresT  = ws + 622592;           // 6451200 (50400 x 128)
  float* pl       = ws + 7073792;          // 50432   (394 x 128)
  float* linv     = ws + 7124224;          // 128
  unsigned short* wc16 = (unsigned short*)(ws + 7124352); // 262144 u16
  unsigned short* st16 = (unsigned short*)(ws + 7255424); // 65536 u16
  // total ws use: ~7,288,192 floats = 29.2 MB

  k_buildT <<<640, 256, 0, stream>>>(input_idx, weighted, order, embW, prev, xT, hT);
  k_zero   <<<384, 256, 0, stream>>>(gi);           // zeros gi AND gh (contiguous)
  k_cvt_wc <<<1024, 256, 0, stream>>>(WcW, wc16);
  k_gemv   <<<dim3(192, 8), 256, 0, stream>>>(Wih, Whh, xT, hT, gi, gh);
  k_state  <<<256, 256, 0, stream>>>(gi, gh, bih, bhh, prev, state_f, st16, out_state);
  k_score_g<<<782, 256, 0, stream>>>(WoW, Wob, st16, scoresT);
  k_score_c<<<800, 256, 0, stream>>>(enc, wc16, Wcb, state_f, enc_idx, scoresT);
  k_sumexp <<<394, 256, 0, stream>>>(scoresT, pl);
  k_merge  <<<1, 1024, 0, stream>>>(pl, linv);
  k_probg  <<<782, 256, 0, stream>>>(scoresT, linv, out);
  k_scatter<<<128, 256, 0, stream>>>(scoresT, linv, enc_idx, input_idx, enc, out, out_w);
}